// Round 8
// baseline (4859.568 us; speedup 1.0000x reference)
//
#include <hip/hip_runtime.h>
#include <stdint.h>

#define Bdim 1024
#define Tdim 512
#define DIN  64
#define DOUT 32
#define DZ   32
#define DH   128
#define Msamp 2
#define NWG  (Bdim / Msamp)   // 512 workgroups -> 2 blocks/CU
#define NTHR 512
#define SP   144              // bf16 row stride (288B): bank-friendly dup-row reads

using s16x8 = __attribute__((ext_vector_type(8))) short;   // 8 x bf16
using f32x4 = __attribute__((ext_vector_type(4))) float;

#define MFMA(a, b, c) __builtin_amdgcn_mfma_f32_16x16x32_bf16((a), (b), (c), 0, 0, 0)

// Raw barrier: LDS visibility only — does NOT drain vmcnt, so global prefetch
// loads issued in P1 stay in flight until their P3 use.
#define BAR() do { asm volatile("s_waitcnt lgkmcnt(0)" ::: "memory"); \
                   __builtin_amdgcn_s_barrier();                      \
                   asm volatile("" ::: "memory"); } while (0)

// ---------------- threefry2x32 (JAX/Random123, 20 rounds) ----------------
__host__ __device__ inline void tf2x32(unsigned k0, unsigned k1, unsigned c0, unsigned c1,
                                       unsigned &o0, unsigned &o1) {
  unsigned ks2 = k0 ^ k1 ^ 0x1BD11BDAu;
  unsigned x0 = c0 + k0, x1 = c1 + k1;
#define TFR(r) { x0 += x1; x1 = (x1 << (r)) | (x1 >> (32 - (r))); x1 ^= x0; }
  TFR(13) TFR(15) TFR(26) TFR(6)
  x0 += k1;  x1 += ks2 + 1u;
  TFR(17) TFR(29) TFR(16) TFR(24)
  x0 += ks2; x1 += k0 + 2u;
  TFR(13) TFR(15) TFR(26) TFR(6)
  x0 += k0;  x1 += k1 + 3u;
  TFR(17) TFR(29) TFR(16) TFR(24)
  x0 += k1;  x1 += ks2 + 4u;
  TFR(13) TFR(15) TFR(26) TFR(6)
  x0 += ks2; x1 += k0 + 5u;
#undef TFR
  o0 = x0; o1 = x1;
}

__device__ inline float erfinv_xla(float x) {
  float w = -log1pf(-x * x);
  float p;
  if (w < 5.0f) {
    w -= 2.5f;
    p = 2.81022636e-08f;
    p = fmaf(p, w, 3.43273939e-07f);
    p = fmaf(p, w, -3.5233877e-06f);
    p = fmaf(p, w, -4.39150654e-06f);
    p = fmaf(p, w, 0.00021858087f);
    p = fmaf(p, w, -0.00125372503f);
    p = fmaf(p, w, -0.00417768164f);
    p = fmaf(p, w, 0.246640727f);
    p = fmaf(p, w, 1.50140941f);
  } else {
    w = sqrtf(w) - 3.0f;
    p = -0.000200214257f;
    p = fmaf(p, w, 0.000100950558f);
    p = fmaf(p, w, 0.00134934322f);
    p = fmaf(p, w, -0.00367342844f);
    p = fmaf(p, w, 0.00573950773f);
    p = fmaf(p, w, -0.0076224613f);
    p = fmaf(p, w, 0.00943887047f);
    p = fmaf(p, w, 1.00167406f);
    p = fmaf(p, w, 2.83297682f);
  }
  return p * x;
}

__device__ inline float bits_to_normal(unsigned bits) {
  float f = __uint_as_float((bits >> 9) | 0x3f800000u) - 1.0f;
  float u = f * 2.0f - 0.99999994f;
  u = fmaxf(u, -0.99999994f);
  return 1.41421356f * erfinv_xla(u);
}

// partitionable threefry: bits[i] = x0 ^ x1 of cipher(key, (0, i))
__device__ inline float jax_normal(unsigned k0, unsigned k1, unsigned idx) {
  unsigned o0, o1;
  tf2x32(k0, k1, 0u, idx, o0, o1);
  return bits_to_normal(o0 ^ o1);
}

// ---------------- helpers ----------------
__device__ inline float clampf(float v) { return fminf(fmaxf(v, -10.0f), 2.0f); }
__device__ inline float tanh_fast(float v) {
  float e = __expf(2.0f * v);
  return 1.0f - __fdividef(2.0f, e + 1.0f);
}
__device__ inline short f2bf(float x) {  // RNE float->bf16
  unsigned u = __float_as_uint(x);
  u = (u + 0x7fffu + ((u >> 16) & 1u)) >> 16;
  return (short)u;
}

// one MFMA B-fragment (16 cols x 32 k) of fp32 W (K x N row-major) as bf16
__device__ inline s16x8 load_frag(const float* __restrict__ W, int N, int kt, int nt, int lane) {
  int k0 = kt * 32 + ((lane >> 4) << 3);
  int n  = nt * 16 + (lane & 15);
  s16x8 f;
#pragma unroll
  for (int e = 0; e < 8; ++e) f[e] = f2bf(W[(size_t)(k0 + e) * N + n]);
  return f;
}

// ---------------- main persistent kernel ----------------
__global__ __launch_bounds__(NTHR, 4) void dssm_main(
    const float* __restrict__ gx, const float* __restrict__ gy,
    const float* __restrict__ pW1, const float* __restrict__ pb1,
    const float* __restrict__ pW2, const float* __restrict__ pb2,
    const float* __restrict__ pW3, const float* __restrict__ pb3,
    const float* __restrict__ qW1, const float* __restrict__ qb1,
    const float* __restrict__ qW2, const float* __restrict__ qb2,
    const float* __restrict__ qW3, const float* __restrict__ qb3,
    const float* __restrict__ eW1, const float* __restrict__ eb1,
    const float* __restrict__ eW2, const float* __restrict__ eb2,
    const float* __restrict__ eW3, const float* __restrict__ eb3,
    const float* __restrict__ z0mu, const float* __restrict__ z0lv,
    float* __restrict__ gout, float* __restrict__ gws,
    unsigned ka0, unsigned ka1, unsigned kb0, unsigned kb1)
{
  __shared__ __align__(16) short in_pq[2 * SP];                 // [z32|x64|y32]
  __shared__ __align__(16) short hpa[2 * SP], hqa[2 * SP], hea[2 * SP];
  __shared__ __align__(16) short hpb[2 * SP], hqb[2 * SP], heb[2 * SP];
  __shared__ float out_q2[2][32][2], out_p2[2][32][2], emit_o2[2][32][2];
  __shared__ float y_f32[4][64];    // 4-deep y ring (fp32 exact), lane = s*32+j
  __shared__ float epsb[8][64];     // 8-step eps ring, lane = s*32+zd

  const int tid  = threadIdx.x;
  const int w    = tid >> 6;
  const int lane = tid & 63;
  const int col  = lane & 15;
  const int g    = lane >> 4;       // 0..3
  const int wg   = blockIdx.x;
  const int base = wg * Msamp;

  // ---- register weight fragments (uniform across waves: 32 frags) ----
  s16x8 f1p[3], f1q[4], f1e, f2[16], f3[8];
#pragma unroll
  for (int i = 0; i < 16; ++i) f2[i] = (s16x8)(short)0;
#pragma unroll
  for (int i = 0; i < 8; ++i) f3[i] = (s16x8)(short)0;

#pragma unroll
  for (int kt = 0; kt < 3; ++kt) f1p[kt] = load_frag(pW1, DH, kt, w, lane);
#pragma unroll
  for (int kt = 0; kt < 4; ++kt) f1q[kt] = load_frag(qW1, DH, kt, w, lane);
  f1e = load_frag(eW1, DH, 0, w, lane);

  if (w < 2) {
#pragma unroll
    for (int nt = 0; nt < 4; ++nt)
#pragma unroll
      for (int kt = 0; kt < 4; ++kt) f2[nt * 4 + kt] = load_frag(pW2, DH, kt, (w & 1) * 4 + nt, lane);
  } else if (w < 4) {
#pragma unroll
    for (int nt = 0; nt < 4; ++nt)
#pragma unroll
      for (int kt = 0; kt < 4; ++kt) f2[nt * 4 + kt] = load_frag(qW2, DH, kt, (w & 1) * 4 + nt, lane);
  } else if (w < 6) {
#pragma unroll
    for (int nt = 0; nt < 4; ++nt)
#pragma unroll
      for (int kt = 0; kt < 4; ++kt) f2[nt * 4 + kt] = load_frag(eW2, DH, kt, (w & 1) * 4 + nt, lane);
  }

  if (w < 4) {
#pragma unroll
    for (int kt = 0; kt < 4; ++kt) f3[kt] = load_frag(eW3, 2 * DOUT, kt, w, lane);
  } else if (w < 6) {
#pragma unroll
    for (int kt = 0; kt < 4; ++kt) { f3[kt]     = load_frag(qW3, 2 * DZ, kt, w - 4, lane);
                                     f3[4 + kt] = load_frag(qW3, 2 * DZ, kt, w - 2, lane); }
  } else {
#pragma unroll
    for (int kt = 0; kt < 4; ++kt) { f3[kt]     = load_frag(pW3, 2 * DZ, kt, w - 6, lane);
                                     f3[4 + kt] = load_frag(pW3, 2 * DZ, kt, w - 4, lane); }
  }

  // ---- biases (per-lane, hoisted) ----
  const float b1p = pb1[w * 16 + col], b1q = qb1[w * 16 + col], b1e = eb1[w * 16 + col];
  float b2[4];
#pragma unroll
  for (int nt = 0; nt < 4; ++nt) {
    int n = ((w & 1) * 4 + nt) * 16 + col;
    b2[nt] = (w < 2) ? pb2[n] : (w < 4) ? qb2[n] : (w < 6) ? eb2[n] : 0.0f;
  }
  float b3a = 0.0f, b3b = 0.0f;
  if (w < 4)      { b3a = eb3[w * 16 + col]; }
  else if (w < 6) { b3a = qb3[(w - 4) * 16 + col]; b3b = qb3[32 + (w - 4) * 16 + col]; }
  else            { b3a = pb3[(w - 6) * 16 + col]; b3b = pb3[32 + (w - 6) * 16 + col]; }

  // ---- hoisted A-fragment pointers (dup-row: row = col&1) ----
  const s16x8* A1 = (const s16x8*)(in_pq + (col & 1) * SP) + g;
  const short* p2s = (w < 2) ? hpa : (w < 4) ? hqa : hea;
  const s16x8* A2 = (const s16x8*)(p2s + (col & 1) * SP) + g;
  short* p2d = (w < 2) ? hpb : (w < 4) ? hqb : heb;
  const short* p3s = (w < 4) ? heb : (w < 6) ? hqb : hpb;
  const s16x8* A3 = (const s16x8*)(p3s + (col & 1) * SP) + g;

  // ---- prologue: t=0 inputs, z0 ----
  if (w < 2) {
    in_pq[w * SP + 32 + lane] = f2bf(gx[((size_t)(base + w) * Tdim) * DIN + lane]);
  } else if (w == 6) {
    int s = lane >> 5, j = lane & 31;
    float yv = gy[((size_t)(base + s) * Tdim) * DOUT + j];
    in_pq[s * SP + 96 + j] = f2bf(yv);
    y_f32[0][lane] = yv;
  } else if (w == 3) {
    int s = lane >> 5, zd = lane & 31;
    float e0 = jax_normal(ka0, ka1, (unsigned)(base + s) * 32u + (unsigned)zd);
    float lv = clampf(z0lv[zd]);
    in_pq[s * SP + zd] = f2bf(z0mu[zd] + __expf(0.5f * lv) * e0);
  }
  BAR();

  float kl_acc = 0.0f, nll_acc = 0.0f;
  float xnext = 0.0f, ynext = 0.0f;

#pragma unroll 1
  for (int t = 0; t <= Tdim; ++t) {
    // ============ PHASE 1: L1 (prior/post/emit) + prefetch + eps batch ============
    if (w < 2 && t < Tdim - 1)
      xnext = gx[((size_t)(base + w) * Tdim + (t + 1)) * DIN + lane];
    if (w == 6 && t < Tdim - 1)
      ynext = gy[((size_t)(base + (lane >> 5)) * Tdim + (t + 1)) * DOUT + (lane & 31)];
    if ((t & 7) == 0 && t < Tdim)   // wave w computes step (t+w)'s 64 eps values
      epsb[w][lane] = jax_normal(kb0, kb1,
          (unsigned)(t + w) * 32768u + (unsigned)base * 32u + (unsigned)lane);

    {
      s16x8 a0 = A1[0], a1 = A1[4], a2 = A1[8], a3 = A1[12];
      f32x4 cE = {0.f, 0.f, 0.f, 0.f};
      cE = MFMA(a0, f1e, cE);                       // emit L1 on z (= z_{t-1})
      float vE = (g & 1) ? cE[1] : cE[0];
      if (g < 2) hea[g * SP + w * 16 + col] = f2bf(tanh_fast(vE + b1e));
      if (t < Tdim) {
        f32x4 cP = {0.f, 0.f, 0.f, 0.f}, cQ = {0.f, 0.f, 0.f, 0.f};
        cP = MFMA(a0, f1p[0], cP); cP = MFMA(a1, f1p[1], cP); cP = MFMA(a2, f1p[2], cP);
        cQ = MFMA(a0, f1q[0], cQ); cQ = MFMA(a1, f1q[1], cQ);
        cQ = MFMA(a2, f1q[2], cQ); cQ = MFMA(a3, f1q[3], cQ);
        float vP = (g & 1) ? cP[1] : cP[0];
        float vQ = (g & 1) ? cQ[1] : cQ[0];
        if (g < 2) {
          hpa[g * SP + w * 16 + col] = f2bf(tanh_fast(vP + b1p));
          hqa[g * SP + w * 16 + col] = f2bf(tanh_fast(vQ + b1q));
        }
      }
    }
    BAR();

    // ============ PHASE 2: L2 slices | KL(t-1) | NLL(t-2) ============
    if (w < 6) {
      if (w >= 4 || t < Tdim) {     // emit-L2 always; p/q-L2 only while stepping
        s16x8 a0 = A2[0], a1 = A2[4], a2 = A2[8], a3 = A2[12];
        f32x4 d0 = {0.f,0.f,0.f,0.f}, d1 = {0.f,0.f,0.f,0.f},
              d2 = {0.f,0.f,0.f,0.f}, d3 = {0.f,0.f,0.f,0.f};
        d0 = MFMA(a0, f2[0],  d0); d0 = MFMA(a1, f2[1],  d0);
        d0 = MFMA(a2, f2[2],  d0); d0 = MFMA(a3, f2[3],  d0);
        d1 = MFMA(a0, f2[4],  d1); d1 = MFMA(a1, f2[5],  d1);
        d1 = MFMA(a2, f2[6],  d1); d1 = MFMA(a3, f2[7],  d1);
        d2 = MFMA(a0, f2[8],  d2); d2 = MFMA(a1, f2[9],  d2);
        d2 = MFMA(a2, f2[10], d2); d2 = MFMA(a3, f2[11], d2);
        d3 = MFMA(a0, f2[12], d3); d3 = MFMA(a1, f2[13], d3);
        d3 = MFMA(a2, f2[14], d3); d3 = MFMA(a3, f2[15], d3);
        float v0 = (g & 1) ? d0[1] : d0[0];
        float v1 = (g & 1) ? d1[1] : d1[0];
        float v2 = (g & 1) ? d2[1] : d2[0];
        float v3 = (g & 1) ? d3[1] : d3[0];
        int nb = (w & 1) * 4;
        if (g < 2) {
          p2d[g * SP + (nb + 0) * 16 + col] = f2bf(tanh_fast(v0 + b2[0]));
          p2d[g * SP + (nb + 1) * 16 + col] = f2bf(tanh_fast(v1 + b2[1]));
          p2d[g * SP + (nb + 2) * 16 + col] = f2bf(tanh_fast(v2 + b2[2]));
          p2d[g * SP + (nb + 3) * 16 + col] = f2bf(tanh_fast(v3 + b2[3]));
        }
      }
    } else if (w == 6) {
      if (t >= 1) {
        int s = lane >> 5, zd = lane & 31;
        float2 q = *(const float2*)&out_q2[s][zd][0];
        float2 p = *(const float2*)&out_p2[s][zd][0];
        float dm = q.x - p.x;
        kl_acc += p.y - q.y + (__expf(q.y) + dm * dm) / (__expf(p.y) + 1e-12f);
      }
    } else {
      if (t >= 2) {
        int s = lane >> 5, j = lane & 31;
        float2 e = *(const float2*)&emit_o2[s][j][0];
        float d = y_f32[(t - 2) & 3][lane] - e.x;
        nll_acc += e.y + d * d * __expf(-e.y);
      }
    }
    BAR();

    // ============ PHASE 3: heads + emit-L3 + z-sample + commits ============
    if (w < 4) {
      // emit L3, n-tile w (output is step t-1's emit)
      s16x8 a0 = A3[0], a1 = A3[4], a2 = A3[8], a3 = A3[12];
      f32x4 e = {0.f, 0.f, 0.f, 0.f};
      e = MFMA(a0, f3[0], e); e = MFMA(a1, f3[1], e);
      e = MFMA(a2, f3[2], e); e = MFMA(a3, f3[3], e);
      float v = ((g & 1) ? e[1] : e[0]) + b3a;
      if (w < 2) {               // mu_y cols w*16..
        if (g < 2) {
          if (t >= 1)
            gout[((size_t)(base + g) * Tdim + (t - 1)) * DOUT + w * 16 + col] = v;
          emit_o2[g][w * 16 + col][0] = v;
        }
        if (t < Tdim - 1) in_pq[w * SP + 32 + lane] = f2bf(xnext);   // commit x(t+1)
      } else {                   // lv_y cols (w-2)*16.. (store clamped)
        if (g < 2) emit_o2[g][(w - 2) * 16 + col][1] = clampf(v);
      }
    } else if (t < Tdim) {
      // q heads (w4,5) / p heads (w6,7): mu + lv for 16 cols each
      s16x8 a0 = A3[0], a1 = A3[4], a2 = A3[8], a3 = A3[12];
      f32x4 cM = {0.f,0.f,0.f,0.f}, cL = {0.f,0.f,0.f,0.f};
      cM = MFMA(a0, f3[0], cM); cM = MFMA(a1, f3[1], cM);
      cM = MFMA(a2, f3[2], cM); cM = MFMA(a3, f3[3], cM);
      cL = MFMA(a0, f3[4], cL); cL = MFMA(a1, f3[5], cL);
      cL = MFMA(a2, f3[6], cL); cL = MFMA(a3, f3[7], cL);
      float mu = ((g & 1) ? cM[1] : cM[0]) + b3a;
      float lv = clampf(((g & 1) ? cL[1] : cL[0]) + b3b);
      if (w < 6) {
        int jc = (w - 4) * 16 + col;
        if (g < 2) {
          float z = mu + __expf(0.5f * lv) * epsb[t & 7][g * 32 + jc];
          in_pq[g * SP + jc] = f2bf(z);                      // z_t for next iter
          *(float2*)&out_q2[g][jc][0] = make_float2(mu, lv);
        }
      } else {
        int jc = (w - 6) * 16 + col;
        if (g < 2) *(float2*)&out_p2[g][jc][0] = make_float2(mu, lv);
        if (w == 6 && t < Tdim - 1) {                        // commit y(t+1)
          in_pq[(lane >> 5) * SP + 96 + (lane & 31)] = f2bf(ynext);
          y_f32[(t + 1) & 3][lane] = ynext;
        }
      }
    }
    BAR();
  }

  // final NLL (step 511): emit_o2 from flush iter, y ring slot (T-1)&3
  if (w == 7) {
    int s = lane >> 5, j = lane & 31;
    float2 e = *(const float2*)&emit_o2[s][j][0];
    float d = y_f32[(Tdim - 1) & 3][lane] - e.x;
    nll_acc += e.y + d * d * __expf(-e.y);
  }

  // per-WG reduction: w7 holds nll, w6 holds kl
  float vn = nll_acc, vk = kl_acc;
#pragma unroll
  for (int o = 32; o > 0; o >>= 1) { vn += __shfl_down(vn, o, 64); vk += __shfl_down(vk, o, 64); }
  if (w == 7 && lane == 0) gws[wg] = vn;
  if (w == 6 && lane == 0) gws[NWG + wg] = vk;
}

// ---------------- finalize: reduce 512 partials ----------------
__global__ void dssm_fin(const float* __restrict__ gws, float* __restrict__ gout) {
  __shared__ float sb[16];
  int tid = threadIdx.x;   // 512
  int w = tid >> 6, lane = tid & 63;
  float vn = gws[tid], vk = gws[NWG + tid];
#pragma unroll
  for (int o = 32; o > 0; o >>= 1) { vn += __shfl_down(vn, o, 64); vk += __shfl_down(vk, o, 64); }
  if (lane == 0) { sb[w] = vn; sb[8 + w] = vk; }
  __syncthreads();
  if (tid == 0) {
    float sn = 0.f, sk = 0.f;
#pragma unroll
    for (int i = 0; i < 8; ++i) { sn += sb[i]; sk += sb[8 + i]; }
    const float inv = 1.0f / (float)((size_t)Bdim * Tdim);
    float nll = 0.5f * (sn * inv + (float)DOUT * 1.8378770664093453f);
    float kl  = 0.5f * (sk * inv - (float)DZ);
    size_t o0 = (size_t)Bdim * Tdim * DOUT;
    gout[o0 + 0] = nll + kl;
    gout[o0 + 1] = nll;
    gout[o0 + 2] = kl;
  }
}

extern "C" void kernel_launch(void* const* d_in, const int* in_sizes, int n_in,
                              void* d_out, int out_size, void* d_ws, size_t ws_size,
                              hipStream_t stream) {
  (void)in_sizes; (void)n_in; (void)out_size; (void)ws_size;
  const float* gx  = (const float*)d_in[0];
  const float* gy  = (const float*)d_in[1];
  const float* pW1 = (const float*)d_in[2];  const float* pb1 = (const float*)d_in[3];
  const float* pW2 = (const float*)d_in[4];  const float* pb2 = (const float*)d_in[5];
  const float* pW3 = (const float*)d_in[6];  const float* pb3 = (const float*)d_in[7];
  const float* qW1 = (const float*)d_in[8];  const float* qb1 = (const float*)d_in[9];
  const float* qW2 = (const float*)d_in[10]; const float* qb2 = (const float*)d_in[11];
  const float* qW3 = (const float*)d_in[12]; const float* qb3 = (const float*)d_in[13];
  const float* eW1 = (const float*)d_in[14]; const float* eb1 = (const float*)d_in[15];
  const float* eW2 = (const float*)d_in[16]; const float* eb2 = (const float*)d_in[17];
  const float* eW3 = (const float*)d_in[18]; const float* eb3 = (const float*)d_in[19];
  const float* z0mu = (const float*)d_in[20];
  const float* z0lv = (const float*)d_in[21];
  float* gout = (float*)d_out;
  float* gws  = (float*)d_ws;

  unsigned ka0, ka1, kb0, kb1;
  tf2x32(0u, 42u, 0u, 0u, ka0, ka1);   // fold_in(key(42), 0) -> eps0 key
  tf2x32(0u, 42u, 0u, 1u, kb0, kb1);   // fold_in(key(42), 1) -> eps key

  dssm_main<<<NWG, NTHR, 0, stream>>>(gx, gy,
      pW1, pb1, pW2, pb2, pW3, pb3,
      qW1, qb1, qW2, qb2, qW3, qb3,
      eW1, eb1, eW2, eb2, eW3, eb3,
      z0mu, z0lv, gout, gws, ka0, ka1, kb0, kb1);
  dssm_fin<<<1, 512, 0, stream>>>(gws, gout);
}

// Round 10
// 1723.533 us; speedup vs baseline: 2.8195x; 2.8195x over previous
//
#include <hip/hip_runtime.h>
#include <stdint.h>

#define Bdim 1024
#define Tdim 512
#define DIN  64
#define DOUT 32
#define DZ   32
#define DH   128
#define Msamp 2
#define NWG  512          // Bdim/Msamp -> 2 blocks/CU
#define NTHR 256          // 4 waves/block -> 8 waves/CU -> 256-reg cap
#define SP   144          // bf16 row stride (288B)

using s16x8 = __attribute__((ext_vector_type(8))) short;   // 8 x bf16
using f32x4 = __attribute__((ext_vector_type(4))) float;

#define MFMA(a, b, c) __builtin_amdgcn_mfma_f32_16x16x32_bf16((a), (b), (c), 0, 0, 0)

// Raw barrier: LDS visibility only — does NOT drain vmcnt (prefetch stays in flight)
#define BAR() do { asm volatile("s_waitcnt lgkmcnt(0)" ::: "memory"); \
                   __builtin_amdgcn_s_barrier();                      \
                   asm volatile("" ::: "memory"); } while (0)

// ---------------- threefry2x32 (JAX/Random123, 20 rounds) ----------------
__host__ __device__ inline void tf2x32(unsigned k0, unsigned k1, unsigned c0, unsigned c1,
                                       unsigned &o0, unsigned &o1) {
  unsigned ks2 = k0 ^ k1 ^ 0x1BD11BDAu;
  unsigned x0 = c0 + k0, x1 = c1 + k1;
#define TFR(r) { x0 += x1; x1 = (x1 << (r)) | (x1 >> (32 - (r))); x1 ^= x0; }
  TFR(13) TFR(15) TFR(26) TFR(6)
  x0 += k1;  x1 += ks2 + 1u;
  TFR(17) TFR(29) TFR(16) TFR(24)
  x0 += ks2; x1 += k0 + 2u;
  TFR(13) TFR(15) TFR(26) TFR(6)
  x0 += k0;  x1 += k1 + 3u;
  TFR(17) TFR(29) TFR(16) TFR(24)
  x0 += k1;  x1 += ks2 + 4u;
  TFR(13) TFR(15) TFR(26) TFR(6)
  x0 += ks2; x1 += k0 + 5u;
#undef TFR
  o0 = x0; o1 = x1;
}

__device__ inline float erfinv_xla(float x) {
  float w = -log1pf(-x * x);
  float p;
  if (w < 5.0f) {
    w -= 2.5f;
    p = 2.81022636e-08f;
    p = fmaf(p, w, 3.43273939e-07f);
    p = fmaf(p, w, -3.5233877e-06f);
    p = fmaf(p, w, -4.39150654e-06f);
    p = fmaf(p, w, 0.00021858087f);
    p = fmaf(p, w, -0.00125372503f);
    p = fmaf(p, w, -0.00417768164f);
    p = fmaf(p, w, 0.246640727f);
    p = fmaf(p, w, 1.50140941f);
  } else {
    w = sqrtf(w) - 3.0f;
    p = -0.000200214257f;
    p = fmaf(p, w, 0.000100950558f);
    p = fmaf(p, w, 0.00134934322f);
    p = fmaf(p, w, -0.00367342844f);
    p = fmaf(p, w, 0.00573950773f);
    p = fmaf(p, w, -0.0076224613f);
    p = fmaf(p, w, 0.00943887047f);
    p = fmaf(p, w, 1.00167406f);
    p = fmaf(p, w, 2.83297682f);
  }
  return p * x;
}

__device__ inline float bits_to_normal(unsigned bits) {
  float f = __uint_as_float((bits >> 9) | 0x3f800000u) - 1.0f;
  float u = f * 2.0f - 0.99999994f;
  u = fmaxf(u, -0.99999994f);
  return 1.41421356f * erfinv_xla(u);
}

// partitionable threefry: bits[i] = x0 ^ x1 of cipher(key, (0, i))
__device__ inline float jax_normal(unsigned k0, unsigned k1, unsigned idx) {
  unsigned o0, o1;
  tf2x32(k0, k1, 0u, idx, o0, o1);
  return bits_to_normal(o0 ^ o1);
}

// ---------------- helpers ----------------
__device__ inline float clampf(float v) { return fminf(fmaxf(v, -10.0f), 2.0f); }
__device__ inline float tanh_fast(float v) {
  float e = __expf(2.0f * v);
  return 1.0f - __fdividef(2.0f, e + 1.0f);
}
__device__ inline short f2bf(float x) {  // RNE float->bf16
  unsigned u = __float_as_uint(x);
  u = (u + 0x7fffu + ((u >> 16) & 1u)) >> 16;
  return (short)u;
}
// dup-row D: c[0]=sample0, c[1]=sample1 in every lane
__device__ inline float sel2(f32x4 c, int g) { return (g & 1) ? c[1] : c[0]; }

// bf16 B-fragment (16 cols x 32 k) of fp32 W (K x N row-major)
__device__ inline s16x8 load_frag(const float* __restrict__ W, int N, int kt, int nt, int lane) {
  int k0 = kt * 32 + ((lane >> 4) << 3);
  int n  = nt * 16 + (lane & 15);
  s16x8 f;
#pragma unroll
  for (int e = 0; e < 8; ++e) f[e] = f2bf(W[(size_t)(k0 + e) * N + n]);
  return f;
}

// ---------------- main persistent kernel ----------------
__global__ __launch_bounds__(NTHR, 2) void dssm_main(
    const float* __restrict__ gx, const float* __restrict__ gy,
    const float* __restrict__ pW1, const float* __restrict__ pb1,
    const float* __restrict__ pW2, const float* __restrict__ pb2,
    const float* __restrict__ pW3, const float* __restrict__ pb3,
    const float* __restrict__ qW1, const float* __restrict__ qb1,
    const float* __restrict__ qW2, const float* __restrict__ qb2,
    const float* __restrict__ qW3, const float* __restrict__ qb3,
    const float* __restrict__ eW1, const float* __restrict__ eb1,
    const float* __restrict__ eW2, const float* __restrict__ eb2,
    const float* __restrict__ eW3, const float* __restrict__ eb3,
    const float* __restrict__ z0mu, const float* __restrict__ z0lv,
    float* __restrict__ gout, float* __restrict__ gws,
    unsigned ka0, unsigned ka1, unsigned kb0, unsigned kb1)
{
  __shared__ __align__(16) short in_pq[2 * SP];                 // [z32|x64|y32]
  __shared__ __align__(16) short hpa[2 * SP], hqa[2 * SP], hea[2 * SP];
  __shared__ __align__(16) short hpb[2 * SP], hqb[2 * SP], heb[2 * SP];
  // weight-fragment pools (loop-invariant)
  __shared__ __align__(16) s16x8 poolE1[8][64];   // e-L1 nt0..7
  __shared__ __align__(16) s16x8 poolQ3[8][64];   // q-head lv: [((nt-2)<<2)|kt]
  __shared__ __align__(16) s16x8 poolP3[8][64];   // p-head lv
  __shared__ __align__(16) s16x8 poolP2[8][64];   // p-L2 kt3, nt0..7
  __shared__ __align__(16) s16x8 poolE2[8][64];   // e-L2 kt3, nt0..7
  __shared__ float out_q2[2][32][2], out_p2[2][32][2], emit_o2[2][32][2];
  __shared__ float y_f32[4][64];    // y ring (fp32 exact), lane = s*32+j
  __shared__ float epsb[8][64];     // eps ring, lane = s*32+zd

  const int tid  = threadIdx.x;
  const int w    = tid >> 6;        // 0..3
  const int lane = tid & 63;
  const int col  = lane & 15;
  const int g    = lane >> 4;       // 0..3 (g<2 owns sample g)
  const int s2   = lane >> 5;       // for 64-wide (2 samples x 32) ops
  const int j32  = lane & 31;
  const int wg   = blockIdx.x;
  const int base = wg * Msamp;

  // ---- register weight fragments: 42 frags = 168 VGPR ----
  s16x8 f1p[6], f1q[8];   // P1: p nt{w,w+4} kt0-2, q nt{w,w+4} kt0-3
  s16x8 f2q[8], f2o[12];  // P2: q nt{w,w+4} kt0-3; p-or-e 4nt x kt0-2
  s16x8 f3[8];            // P3 role frags

#pragma unroll
  for (int j = 0; j < 2; ++j) {
#pragma unroll
    for (int kt = 0; kt < 3; ++kt) f1p[j * 3 + kt] = load_frag(pW1, DH, kt, w + j * 4, lane);
#pragma unroll
    for (int kt = 0; kt < 4; ++kt) f1q[j * 4 + kt] = load_frag(qW1, DH, kt, w + j * 4, lane);
#pragma unroll
    for (int kt = 0; kt < 4; ++kt) f2q[j * 4 + kt] = load_frag(qW2, DH, kt, w + j * 4, lane);
  }
  {
    const float* W2o = (w < 2) ? pW2 : eW2;
#pragma unroll
    for (int nt = 0; nt < 4; ++nt)
#pragma unroll
      for (int kt = 0; kt < 3; ++kt)
        f2o[nt * 3 + kt] = load_frag(W2o, DH, kt, (w & 1) * 4 + nt, lane);
  }
  {
    const float* W3 = (w == 0) ? qW3 : (w == 1) ? pW3 : eW3;
    int nb = (w == 3) ? 2 : 0;
#pragma unroll
    for (int j = 0; j < 2; ++j)
#pragma unroll
      for (int kt = 0; kt < 4; ++kt) f3[j * 4 + kt] = load_frag(W3, 64, kt, nb + j, lane);
  }

  // ---- LDS pools: each wave fills frag ids {w, w+4} of each pool ----
#pragma unroll
  for (int r = 0; r < 2; ++r) {
    int f = w + r * 4;
    poolE1[f][lane] = load_frag(eW1, DH, 0, f, lane);
    poolQ3[f][lane] = load_frag(qW3, 64, f & 3, 2 + (f >> 2), lane);
    poolP3[f][lane] = load_frag(pW3, 64, f & 3, 2 + (f >> 2), lane);
    poolP2[f][lane] = load_frag(pW2, DH, 3, f, lane);
    poolE2[f][lane] = load_frag(eW2, DH, 3, f, lane);
  }

  // ---- biases ----
  const float b1p0 = pb1[w * 16 + col], b1p1 = pb1[(w + 4) * 16 + col];
  const float b1q0 = qb1[w * 16 + col], b1q1 = qb1[(w + 4) * 16 + col];
  const float b1e0 = eb1[w * 16 + col], b1e1 = eb1[(w + 4) * 16 + col];
  const float b2q0 = qb2[w * 16 + col], b2q1 = qb2[(w + 4) * 16 + col];
  float b2o[4];
  {
    const float* ob = (w < 2) ? pb2 : eb2;
#pragma unroll
    for (int nt = 0; nt < 4; ++nt) b2o[nt] = ob[((w & 1) * 4 + nt) * 16 + col];
  }
  float b3[4] = {0.f, 0.f, 0.f, 0.f};
  if (w == 0)      { b3[0] = qb3[col]; b3[1] = qb3[16 + col]; b3[2] = qb3[32 + col]; b3[3] = qb3[48 + col]; }
  else if (w == 1) { b3[0] = pb3[col]; b3[1] = pb3[16 + col]; b3[2] = pb3[32 + col]; b3[3] = pb3[48 + col]; }
  else if (w == 2) { b3[0] = eb3[col]; b3[1] = eb3[16 + col]; }
  else             { b3[0] = eb3[32 + col]; b3[1] = eb3[48 + col]; }

  // ---- hoisted A pointers (dup-row: row = col&1) ----
  const short* A1  = in_pq + (col & 1) * SP + g * 8;
  const short* A2q = hqa + (col & 1) * SP + g * 8;
  const short* A2o = ((w < 2) ? hpa : hea) + (col & 1) * SP + g * 8;
  const short* A3  = ((w == 0) ? hqb : (w == 1) ? hpb : heb) + (col & 1) * SP + g * 8;
  short* h2o = (w < 2) ? hpb : heb;

  // ---- prologue: t=0 inputs, z0 ----
  if (w < 2) {
    in_pq[w * SP + 32 + lane] = f2bf(gx[((size_t)(base + w) * Tdim) * DIN + lane]);
  } else if (w == 2) {
    float yv = gy[((size_t)(base + s2) * Tdim) * DOUT + j32];
    in_pq[s2 * SP + 96 + j32] = f2bf(yv);
    y_f32[0][lane] = yv;
  } else {
    float e0 = jax_normal(ka0, ka1, (unsigned)(base + s2) * 32u + (unsigned)j32);
    float lv = clampf(z0lv[j32]);
    in_pq[s2 * SP + j32] = f2bf(z0mu[j32] + __expf(0.5f * lv) * e0);
  }
  BAR();

  float kl_acc = 0.0f, nll_acc = 0.0f;
  float xn = 0.0f, yn = 0.0f;

#pragma unroll 1
  for (int t = 0; t <= Tdim; ++t) {
    // ======== PHASE 1: L1 (p/q/e) | prefetch | eps batch | KL(t-1) | NLL(t-2) ========
    if (t < Tdim - 1) {
      if (w < 2)       xn = gx[((size_t)(base + w) * Tdim + (t + 1)) * DIN + lane];
      else if (w == 2) yn = gy[((size_t)(base + s2) * Tdim + (t + 1)) * DOUT + j32];
    }
    if ((t & 7) == 0 && t < Tdim) {
      epsb[w][lane]     = jax_normal(kb0, kb1, (unsigned)(t + w) * 32768u + (unsigned)base * 32u + lane);
      epsb[w + 4][lane] = jax_normal(kb0, kb1, (unsigned)(t + w + 4) * 32768u + (unsigned)base * 32u + lane);
    }
    {
      s16x8 a0 = *(const s16x8*)A1,        a1 = *(const s16x8*)(A1 + 32);
      s16x8 a2 = *(const s16x8*)(A1 + 64), a3 = *(const s16x8*)(A1 + 96);
      const f32x4 z4 = {0.f, 0.f, 0.f, 0.f};
      f32x4 cE0 = MFMA(a0, poolE1[w][lane], z4);
      f32x4 cE1 = MFMA(a0, poolE1[w + 4][lane], z4);
      if (g < 2) {
        hea[g * SP + w * 16 + col]       = f2bf(tanh_fast(sel2(cE0, g) + b1e0));
        hea[g * SP + (w + 4) * 16 + col] = f2bf(tanh_fast(sel2(cE1, g) + b1e1));
      }
      if (t < Tdim) {
        f32x4 cP0 = z4, cP1 = z4, cQ0 = z4, cQ1 = z4;
        cP0 = MFMA(a0, f1p[0], cP0); cP0 = MFMA(a1, f1p[1], cP0); cP0 = MFMA(a2, f1p[2], cP0);
        cP1 = MFMA(a0, f1p[3], cP1); cP1 = MFMA(a1, f1p[4], cP1); cP1 = MFMA(a2, f1p[5], cP1);
        cQ0 = MFMA(a0, f1q[0], cQ0); cQ0 = MFMA(a1, f1q[1], cQ0);
        cQ0 = MFMA(a2, f1q[2], cQ0); cQ0 = MFMA(a3, f1q[3], cQ0);
        cQ1 = MFMA(a0, f1q[4], cQ1); cQ1 = MFMA(a1, f1q[5], cQ1);
        cQ1 = MFMA(a2, f1q[6], cQ1); cQ1 = MFMA(a3, f1q[7], cQ1);
        if (g < 2) {
          hpa[g * SP + w * 16 + col]       = f2bf(tanh_fast(sel2(cP0, g) + b1p0));
          hpa[g * SP + (w + 4) * 16 + col] = f2bf(tanh_fast(sel2(cP1, g) + b1p1));
          hqa[g * SP + w * 16 + col]       = f2bf(tanh_fast(sel2(cQ0, g) + b1q0));
          hqa[g * SP + (w + 4) * 16 + col] = f2bf(tanh_fast(sel2(cQ1, g) + b1q1));
        }
      }
    }
    if (w == 1 && t >= 1) {   // KL(t-1): out_* written P3(t-1)
      float2 q = *(const float2*)&out_q2[s2][j32][0];
      float2 p = *(const float2*)&out_p2[s2][j32][0];
      float dm = q.x - p.x;
      kl_acc += p.y - q.y + (__expf(q.y) + dm * dm) / (__expf(p.y) + 1e-12f);
    }
    if (w == 2 && t >= 2) {   // NLL(t-2): emit_o2 written P3(t-1) = emit(t-2)
      float2 e = *(const float2*)&emit_o2[s2][j32][0];
      float d = y_f32[(t - 2) & 3][lane] - e.x;
      nll_acc += e.y + d * d * __expf(-e.y);
    }
    BAR();

    // ======== PHASE 2: L2 (q + p-or-e) | x/y commits ========
    {
      const f32x4 z4 = {0.f, 0.f, 0.f, 0.f};
      if (t < Tdim) {
        s16x8 a0 = *(const s16x8*)A2q,        a1 = *(const s16x8*)(A2q + 32);
        s16x8 a2 = *(const s16x8*)(A2q + 64), a3 = *(const s16x8*)(A2q + 96);
        f32x4 c0 = z4, c1 = z4;
        c0 = MFMA(a0, f2q[0], c0); c0 = MFMA(a1, f2q[1], c0);
        c0 = MFMA(a2, f2q[2], c0); c0 = MFMA(a3, f2q[3], c0);
        c1 = MFMA(a0, f2q[4], c1); c1 = MFMA(a1, f2q[5], c1);
        c1 = MFMA(a2, f2q[6], c1); c1 = MFMA(a3, f2q[7], c1);
        if (g < 2) {
          hqb[g * SP + w * 16 + col]       = f2bf(tanh_fast(sel2(c0, g) + b2q0));
          hqb[g * SP + (w + 4) * 16 + col] = f2bf(tanh_fast(sel2(c1, g) + b2q1));
        }
      }
      if (w >= 2 || t < Tdim) {   // e-L2 always; p-L2 only while stepping
        s16x8 a0 = *(const s16x8*)A2o,        a1 = *(const s16x8*)(A2o + 32);
        s16x8 a2 = *(const s16x8*)(A2o + 64), a3 = *(const s16x8*)(A2o + 96);
        f32x4 d0 = z4, d1 = z4, d2 = z4, d3 = z4;
        d0 = MFMA(a0, f2o[0],  d0); d0 = MFMA(a1, f2o[1],  d0); d0 = MFMA(a2, f2o[2],  d0);
        d1 = MFMA(a0, f2o[3],  d1); d1 = MFMA(a1, f2o[4],  d1); d1 = MFMA(a2, f2o[5],  d1);
        d2 = MFMA(a0, f2o[6],  d2); d2 = MFMA(a1, f2o[7],  d2); d2 = MFMA(a2, f2o[8],  d2);
        d3 = MFMA(a0, f2o[9],  d3); d3 = MFMA(a1, f2o[10], d3); d3 = MFMA(a2, f2o[11], d3);
        int nb = (w & 1) * 4;
        if (w < 2) {
          d0 = MFMA(a3, poolP2[nb + 0][lane], d0);
          d1 = MFMA(a3, poolP2[nb + 1][lane], d1);
          d2 = MFMA(a3, poolP2[nb + 2][lane], d2);
          d3 = MFMA(a3, poolP2[nb + 3][lane], d3);
        } else {
          d0 = MFMA(a3, poolE2[nb + 0][lane], d0);
          d1 = MFMA(a3, poolE2[nb + 1][lane], d1);
          d2 = MFMA(a3, poolE2[nb + 2][lane], d2);
          d3 = MFMA(a3, poolE2[nb + 3][lane], d3);
        }
        if (g < 2) {
          h2o[g * SP + (nb + 0) * 16 + col] = f2bf(tanh_fast(sel2(d0, g) + b2o[0]));
          h2o[g * SP + (nb + 1) * 16 + col] = f2bf(tanh_fast(sel2(d1, g) + b2o[1]));
          h2o[g * SP + (nb + 2) * 16 + col] = f2bf(tanh_fast(sel2(d2, g) + b2o[2]));
          h2o[g * SP + (nb + 3) * 16 + col] = f2bf(tanh_fast(sel2(d3, g) + b2o[3]));
        }
      }
      if (t < Tdim - 1) {   // commit x/y(t+1) (in_pq x/y only read in P1)
        if (w < 2)       in_pq[w * SP + 32 + lane] = f2bf(xn);
        else if (w == 2) { in_pq[s2 * SP + 96 + j32] = f2bf(yn); y_f32[(t + 1) & 3][lane] = yn; }
      }
    }
    BAR();

    // ======== PHASE 3: heads + emit-L3 + z-sample ========
    {
      const f32x4 z4 = {0.f, 0.f, 0.f, 0.f};
      if (w < 2) {
        if (t < Tdim) {
          s16x8 a0 = *(const s16x8*)A3,        a1 = *(const s16x8*)(A3 + 32);
          s16x8 a2 = *(const s16x8*)(A3 + 64), a3 = *(const s16x8*)(A3 + 96);
          f32x4 cM0 = z4, cM1 = z4, cL0 = z4, cL1 = z4;
          cM0 = MFMA(a0, f3[0], cM0); cM0 = MFMA(a1, f3[1], cM0);
          cM0 = MFMA(a2, f3[2], cM0); cM0 = MFMA(a3, f3[3], cM0);
          cM1 = MFMA(a0, f3[4], cM1); cM1 = MFMA(a1, f3[5], cM1);
          cM1 = MFMA(a2, f3[6], cM1); cM1 = MFMA(a3, f3[7], cM1);
          if (w == 0) {
            cL0 = MFMA(a0, poolQ3[0][lane], cL0); cL0 = MFMA(a1, poolQ3[1][lane], cL0);
            cL0 = MFMA(a2, poolQ3[2][lane], cL0); cL0 = MFMA(a3, poolQ3[3][lane], cL0);
            cL1 = MFMA(a0, poolQ3[4][lane], cL1); cL1 = MFMA(a1, poolQ3[5][lane], cL1);
            cL1 = MFMA(a2, poolQ3[6][lane], cL1); cL1 = MFMA(a3, poolQ3[7][lane], cL1);
          } else {
            cL0 = MFMA(a0, poolP3[0][lane], cL0); cL0 = MFMA(a1, poolP3[1][lane], cL0);
            cL0 = MFMA(a2, poolP3[2][lane], cL0); cL0 = MFMA(a3, poolP3[3][lane], cL0);
            cL1 = MFMA(a0, poolP3[4][lane], cL1); cL1 = MFMA(a1, poolP3[5][lane], cL1);
            cL1 = MFMA(a2, poolP3[6][lane], cL1); cL1 = MFMA(a3, poolP3[7][lane], cL1);
          }
          float mu0 = sel2(cM0, g) + b3[0];
          float mu1 = sel2(cM1, g) + b3[1];
          float lv0 = clampf(sel2(cL0, g) + b3[2]);
          float lv1 = clampf(sel2(cL1, g) + b3[3]);
          if (g < 2) {
            if (w == 0) {   // q-head: sample z_t, stash for KL
              float z0v = mu0 + __expf(0.5f * lv0) * epsb[t & 7][g * 32 + col];
              float z1v = mu1 + __expf(0.5f * lv1) * epsb[t & 7][g * 32 + 16 + col];
              in_pq[g * SP + col]      = f2bf(z0v);
              in_pq[g * SP + 16 + col] = f2bf(z1v);
              *(float2*)&out_q2[g][col][0]      = make_float2(mu0, lv0);
              *(float2*)&out_q2[g][16 + col][0] = make_float2(mu1, lv1);
            } else {        // p-head
              *(float2*)&out_p2[g][col][0]      = make_float2(mu0, lv0);
              *(float2*)&out_p2[g][16 + col][0] = make_float2(mu1, lv1);
            }
          }
        }
      } else {
        // e-L3 (always; produces emit(t-1))
        s16x8 a0 = *(const s16x8*)A3,        a1 = *(const s16x8*)(A3 + 32);
        s16x8 a2 = *(const s16x8*)(A3 + 64), a3 = *(const s16x8*)(A3 + 96);
        f32x4 c0 = z4, c1 = z4;
        c0 = MFMA(a0, f3[0], c0); c0 = MFMA(a1, f3[1], c0);
        c0 = MFMA(a2, f3[2], c0); c0 = MFMA(a3, f3[3], c0);
        c1 = MFMA(a0, f3[4], c1); c1 = MFMA(a1, f3[5], c1);
        c1 = MFMA(a2, f3[6], c1); c1 = MFMA(a3, f3[7], c1);
        float v0 = sel2(c0, g) + b3[0];
        float v1 = sel2(c1, g) + b3[1];
        if (g < 2) {
          if (w == 2) {   // mu_y cols {col, 16+col}
            if (t >= 1) {
              size_t ro = ((size_t)(base + g) * Tdim + (t - 1)) * DOUT;
              gout[ro + col] = v0;
              gout[ro + 16 + col] = v1;
            }
            emit_o2[g][col][0]      = v0;
            emit_o2[g][16 + col][0] = v1;
          } else {        // lv_y cols {32+col, 48+col} -> stored clamped
            emit_o2[g][col][1]      = clampf(v0);
            emit_o2[g][16 + col][1] = clampf(v1);
          }
        }
      }
    }
    BAR();
  }

  // final NLL (step 511): emit_o2 from flush iter, y ring slot (T-1)&3
  if (w == 2) {
    float2 e = *(const float2*)&emit_o2[s2][j32][0];
    float d = y_f32[(Tdim - 1) & 3][lane] - e.x;
    nll_acc += e.y + d * d * __expf(-e.y);
  }

  // per-WG reduction: w2 holds nll, w1 holds kl
  float vn = nll_acc, vk = kl_acc;
#pragma unroll
  for (int o = 32; o > 0; o >>= 1) { vn += __shfl_down(vn, o, 64); vk += __shfl_down(vk, o, 64); }
  if (w == 2 && lane == 0) gws[wg] = vn;
  if (w == 1 && lane == 0) gws[NWG + wg] = vk;
}

// ---------------- finalize: reduce 512 partials ----------------
__global__ void dssm_fin(const float* __restrict__ gws, float* __restrict__ gout) {
  __shared__ float sb[16];
  int tid = threadIdx.x;   // 512
  int w = tid >> 6, lane = tid & 63;
  float vn = gws[tid], vk = gws[NWG + tid];
#pragma unroll
  for (int o = 32; o > 0; o >>= 1) { vn += __shfl_down(vn, o, 64); vk += __shfl_down(vk, o, 64); }
  if (lane == 0) { sb[w] = vn; sb[8 + w] = vk; }
  __syncthreads();
  if (tid == 0) {
    float sn = 0.f, sk = 0.f;
#pragma unroll
    for (int i = 0; i < 8; ++i) { sn += sb[i]; sk += sb[8 + i]; }
    const float inv = 1.0f / (float)((size_t)Bdim * Tdim);
    float nll = 0.5f * (sn * inv + (float)DOUT * 1.8378770664093453f);
    float kl  = 0.5f * (sk * inv - (float)DZ);
    size_t o0 = (size_t)Bdim * Tdim * DOUT;
    gout[o0 + 0] = nll + kl;
    gout[o0 + 1] = nll;
    gout[o0 + 2] = kl;
  }
}

extern "C" void kernel_launch(void* const* d_in, const int* in_sizes, int n_in,
                              void* d_out, int out_size, void* d_ws, size_t ws_size,
                              hipStream_t stream) {
  (void)in_sizes; (void)n_in; (void)out_size; (void)ws_size;
  const float* gx  = (const float*)d_in[0];
  const float* gy  = (const float*)d_in[1];
  const float* pW1 = (const float*)d_in[2];  const float* pb1 = (const float*)d_in[3];
  const float* pW2 = (const float*)d_in[4];  const float* pb2 = (const float*)d_in[5];
  const float* pW3 = (const float*)d_in[6];  const float* pb3 = (const float*)d_in[7];
  const float* qW1 = (const float*)d_in[8];  const float* qb1 = (const float*)d_in[9];
  const float* qW2 = (const float*)d_in[10]; const float* qb2 = (const float*)d_in[11];
  const float* qW3 = (const float*)d_in[12]; const float* qb3 = (const float*)d_in[13];
  const float* eW1 = (const float*)d_in[14]; const float* eb1 = (const float*)d_in[15];
  const float* eW2 = (const float*)d_in[16]; const float* eb2 = (const float*)d_in[17];
  const float* eW3 = (const float*)d_in[18]; const float* eb3 = (const float*)d_in[19];
  const float* z0mu = (const float*)d_in[20];
  const float* z0lv = (const float*)d_in[21];
  float* gout = (float*)d_out;
  float* gws  = (float*)d_ws;

  unsigned ka0, ka1, kb0, kb1;
  tf2x32(0u, 42u, 0u, 0u, ka0, ka1);   // fold_in(key(42), 0) -> eps0 key
  tf2x32(0u, 42u, 0u, 1u, kb0, kb1);   // fold_in(key(42), 1) -> eps key

  dssm_main<<<NWG, NTHR, 0, stream>>>(gx, gy,
      pW1, pb1, pW2, pb2, pW3, pb3,
      qW1, qb1, qW2, qb2, qW3, qb3,
      eW1, eb1, eW2, eb2, eW3, eb3,
      z0mu, z0lv, gout, gws, ka0, ka1, kb0, kb1);
  dssm_fin<<<1, 512, 0, stream>>>(gws, gout);
}

// Round 11
// 826.579 us; speedup vs baseline: 5.8791x; 2.0851x over previous
//
#include <hip/hip_runtime.h>
#include <stdint.h>

#define Bdim 1024
#define Tdim 512
#define DIN  64
#define DOUT 32
#define DZ   32
#define DH   128
#define Msamp 4
#define NWG  256          // Bdim/Msamp -> 1 block/CU
#define NTHR 1024         // 16 waves -> 4 waves/SIMD (VGPR cap 128)
#define SP   144          // bf16 row stride (288B)

using s16x8 = __attribute__((ext_vector_type(8))) short;   // 8 x bf16
using f32x4 = __attribute__((ext_vector_type(4))) float;

#define MFMA(a, b, c) __builtin_amdgcn_mfma_f32_16x16x32_bf16((a), (b), (c), 0, 0, 0)

// Raw barrier: LDS visibility only — does NOT drain vmcnt (prefetch stays in flight)
#define BAR() do { asm volatile("s_waitcnt lgkmcnt(0)" ::: "memory"); \
                   __builtin_amdgcn_s_barrier();                      \
                   asm volatile("" ::: "memory"); } while (0)

// ---------------- threefry2x32 (JAX/Random123, 20 rounds) ----------------
__host__ __device__ inline void tf2x32(unsigned k0, unsigned k1, unsigned c0, unsigned c1,
                                       unsigned &o0, unsigned &o1) {
  unsigned ks2 = k0 ^ k1 ^ 0x1BD11BDAu;
  unsigned x0 = c0 + k0, x1 = c1 + k1;
#define TFR(r) { x0 += x1; x1 = (x1 << (r)) | (x1 >> (32 - (r))); x1 ^= x0; }
  TFR(13) TFR(15) TFR(26) TFR(6)
  x0 += k1;  x1 += ks2 + 1u;
  TFR(17) TFR(29) TFR(16) TFR(24)
  x0 += ks2; x1 += k0 + 2u;
  TFR(13) TFR(15) TFR(26) TFR(6)
  x0 += k0;  x1 += k1 + 3u;
  TFR(17) TFR(29) TFR(16) TFR(24)
  x0 += k1;  x1 += ks2 + 4u;
  TFR(13) TFR(15) TFR(26) TFR(6)
  x0 += ks2; x1 += k0 + 5u;
#undef TFR
  o0 = x0; o1 = x1;
}

__device__ inline float erfinv_xla(float x) {
  float w = -log1pf(-x * x);
  float p;
  if (w < 5.0f) {
    w -= 2.5f;
    p = 2.81022636e-08f;
    p = fmaf(p, w, 3.43273939e-07f);
    p = fmaf(p, w, -3.5233877e-06f);
    p = fmaf(p, w, -4.39150654e-06f);
    p = fmaf(p, w, 0.00021858087f);
    p = fmaf(p, w, -0.00125372503f);
    p = fmaf(p, w, -0.00417768164f);
    p = fmaf(p, w, 0.246640727f);
    p = fmaf(p, w, 1.50140941f);
  } else {
    w = sqrtf(w) - 3.0f;
    p = -0.000200214257f;
    p = fmaf(p, w, 0.000100950558f);
    p = fmaf(p, w, 0.00134934322f);
    p = fmaf(p, w, -0.00367342844f);
    p = fmaf(p, w, 0.00573950773f);
    p = fmaf(p, w, -0.0076224613f);
    p = fmaf(p, w, 0.00943887047f);
    p = fmaf(p, w, 1.00167406f);
    p = fmaf(p, w, 2.83297682f);
  }
  return p * x;
}

__device__ inline float bits_to_normal(unsigned bits) {
  float f = __uint_as_float((bits >> 9) | 0x3f800000u) - 1.0f;
  float u = f * 2.0f - 0.99999994f;
  u = fmaxf(u, -0.99999994f);
  return 1.41421356f * erfinv_xla(u);
}

// partitionable threefry: bits[i] = x0 ^ x1 of cipher(key, (0, i))
__device__ inline float jax_normal(unsigned k0, unsigned k1, unsigned idx) {
  unsigned o0, o1;
  tf2x32(k0, k1, 0u, idx, o0, o1);
  return bits_to_normal(o0 ^ o1);
}

// ---------------- helpers ----------------
__device__ inline float clampf(float v) { return fminf(fmaxf(v, -10.0f), 2.0f); }
__device__ inline float tanh_fast(float v) {
  float e = __expf(2.0f * v);
  return 1.0f - __fdividef(2.0f, e + 1.0f);
}
__device__ inline short f2bf(float x) {  // RNE float->bf16
  unsigned u = __float_as_uint(x);
  u = (u + 0x7fffu + ((u >> 16) & 1u)) >> 16;
  return (short)u;
}
// dup-row (row = col&3) => every lane's c[r] holds sample r; pick sample g
__device__ inline float sel4(f32x4 v, int g) {
  float r = v[0];
  r = (g == 1) ? v[1] : r;
  r = (g == 2) ? v[2] : r;
  r = (g == 3) ? v[3] : r;
  return r;
}

// bf16 B-fragment (16 cols x 32 k) of fp32 W (K x N row-major)
__device__ inline s16x8 load_frag(const float* __restrict__ W, int N, int kt, int nt, int lane) {
  int k0 = kt * 32 + ((lane >> 4) << 3);
  int n  = nt * 16 + (lane & 15);
  s16x8 f;
#pragma unroll
  for (int e = 0; e < 8; ++e) f[e] = f2bf(W[(size_t)(k0 + e) * N + n]);
  return f;
}

// ---------------- main persistent kernel ----------------
__global__ __launch_bounds__(NTHR, 4) void dssm_main(
    const float* __restrict__ gx, const float* __restrict__ gy,
    const float* __restrict__ pW1, const float* __restrict__ pb1,
    const float* __restrict__ pW2, const float* __restrict__ pb2,
    const float* __restrict__ pW3, const float* __restrict__ pb3,
    const float* __restrict__ qW1, const float* __restrict__ qb1,
    const float* __restrict__ qW2, const float* __restrict__ qb2,
    const float* __restrict__ qW3, const float* __restrict__ qb3,
    const float* __restrict__ eW1, const float* __restrict__ eb1,
    const float* __restrict__ eW2, const float* __restrict__ eb2,
    const float* __restrict__ eW3, const float* __restrict__ eb3,
    const float* __restrict__ z0mu, const float* __restrict__ z0lv,
    float* __restrict__ gout, float* __restrict__ gws,
    unsigned ka0, unsigned ka1, unsigned kb0, unsigned kb1)
{
  __shared__ __align__(16) short in_pq[4 * SP];                 // [z32|x64|y32] x 4 samples
  __shared__ __align__(16) short hpa[4 * SP], hqa[4 * SP], hea[4 * SP];
  __shared__ __align__(16) short hpb[4 * SP], hqb[4 * SP], heb[4 * SP];
  __shared__ __align__(16) s16x8 poolQ3[16][64];   // qW3 all 4 nt x 4 kt (slot = nt*4+kt)
  __shared__ __align__(16) s16x8 poolP3[16][64];   // pW3 same
  __shared__ float out_q2[4][32][2], out_p2[4][32][2], emit_o2[4][32][2];
  __shared__ float y_f32[4][128];   // y ring (fp32), idx = s*32+j
  __shared__ float epsb[4][128];    // eps ring slot t&3, idx = s*32+zd
  __shared__ float redsb[4];

  const int tid  = threadIdx.x;
  const int w    = tid >> 6;        // 0..15
  const int lane = tid & 63;
  const int col  = lane & 15;
  const int g    = lane >> 4;       // sample 0..3
  const int wg   = blockIdx.x;
  const int base = wg * Msamp;
  const int ww   = w & 7;
  const int nt16 = ww * 16;

  // ---- register weight fragments (<=12 frags = 48 VGPR) ----
  s16x8 fL1[4], fL2[4], fX[4];
  if (w < 8) {
#pragma unroll
    for (int kt = 0; kt < 4; ++kt) fL1[kt] = load_frag(qW1, DH, kt, w, lane);
#pragma unroll
    for (int kt = 0; kt < 4; ++kt) fL2[kt] = load_frag(qW2, DH, kt, w, lane);
    if (w >= 4) {
#pragma unroll
      for (int kt = 0; kt < 4; ++kt) fX[kt] = load_frag(eW3, 64, kt, w - 4, lane);
    }
  } else {
#pragma unroll
    for (int kt = 0; kt < 3; ++kt) fL1[kt] = load_frag(pW1, DH, kt, ww, lane);
    fL1[3] = load_frag(eW1, DH, 0, ww, lane);     // e-L1 frag rides in slot 3
#pragma unroll
    for (int kt = 0; kt < 4; ++kt) fL2[kt] = load_frag(pW2, DH, kt, ww, lane);
#pragma unroll
    for (int kt = 0; kt < 4; ++kt) fX[kt]  = load_frag(eW2, DH, kt, ww, lane);
  }
  // ---- LDS pools: each wave fills 2 slots ----
  {
    int s0 = 2 * ww;
    if (w < 8) {
      poolQ3[s0][lane]     = load_frag(qW3, 64, s0 & 3, s0 >> 2, lane);
      poolQ3[s0 + 1][lane] = load_frag(qW3, 64, (s0 + 1) & 3, (s0 + 1) >> 2, lane);
    } else {
      poolP3[s0][lane]     = load_frag(pW3, 64, s0 & 3, s0 >> 2, lane);
      poolP3[s0 + 1][lane] = load_frag(pW3, 64, (s0 + 1) & 3, (s0 + 1) >> 2, lane);
    }
  }

  // ---- biases ----
  float b1, b2, b1e = 0.f, b2e = 0.f, b3m = 0.f, b3l = 0.f;
  if (w < 8) {
    b1 = qb1[nt16 + col]; b2 = qb2[nt16 + col];
    if (w < 2)      { b3m = qb3[w * 16 + col];       b3l = qb3[32 + w * 16 + col]; }
    else if (w < 4) { b3m = pb3[(w - 2) * 16 + col]; b3l = pb3[32 + (w - 2) * 16 + col]; }
    else            { b3m = eb3[(w - 4) * 16 + col]; }
  } else {
    b1 = pb1[nt16 + col]; b2 = pb2[nt16 + col];
    b1e = eb1[nt16 + col]; b2e = eb2[nt16 + col];
  }

  // ---- hoisted A pointers (dup-row: row = col&3) ----
  const int aoff = (col & 3) * SP + g * 8;
  const short* A1  = in_pq + aoff;
  const short* A2  = ((w < 8) ? hqa : hpa) + aoff;
  const short* A2e = hea + aoff;
  const short* A3  = ((w < 2) ? hqb : (w < 4) ? hpb : heb) + aoff;

  // ---- prologue: t=0 inputs, z0 ----
  if (w < 4) {
    in_pq[w * SP + 32 + lane] = f2bf(gx[((size_t)(base + w) * Tdim) * DIN + lane]);
  } else if (w == 4 || w == 5) {
    int off = (w - 4) * 64 + lane;
    float yv = gy[((size_t)(base + (off >> 5)) * Tdim) * DOUT + (off & 31)];
    in_pq[(off >> 5) * SP + 96 + (off & 31)] = f2bf(yv);
    y_f32[0][off] = yv;
  } else if (w == 6 || w == 7) {
    int off = (w - 6) * 64 + lane;
    float e0 = jax_normal(ka0, ka1, (unsigned)base * 32u + (unsigned)off);
    float lv = clampf(z0lv[off & 31]);
    in_pq[(off >> 5) * SP + (off & 31)] = f2bf(z0mu[off & 31] + __expf(0.5f * lv) * e0);
  }
  BAR();

  float kl_acc = 0.0f, nll_acc = 0.0f;
  float xn = 0.0f, yn = 0.0f;

#pragma unroll 1
  for (int t = 0; t <= Tdim; ++t) {
    // ======== PHASE 1: L1 (q | p+e) + prefetch + eps burst ========
    if (w < 4 && t < Tdim - 1)
      xn = gx[((size_t)(base + w) * Tdim + (t + 1)) * DIN + lane];
    if ((w == 4 || w == 5) && t < Tdim - 1) {
      int off = (w - 4) * 64 + lane;
      yn = gy[((size_t)(base + (off >> 5)) * Tdim + (t + 1)) * DOUT + (off & 31)];
    }
    if (w >= 8 && (t & 3) == 0 && t < Tdim) {   // fill slots t..t+3
      int k = (w - 8) >> 1, off = ((w - 8) & 1) * 64 + lane;
      epsb[k][off] = jax_normal(kb0, kb1,
          (unsigned)(t + k) * 32768u + (unsigned)base * 32u + (unsigned)off);
    }
    {
      s16x8 a0 = *(const s16x8*)A1,        a1 = *(const s16x8*)(A1 + 32);
      s16x8 a2 = *(const s16x8*)(A1 + 64), a3 = *(const s16x8*)(A1 + 96);
      const f32x4 z4 = {0.f, 0.f, 0.f, 0.f};
      if (w < 8) {
        if (t < Tdim) {
          f32x4 c = z4;
          c = MFMA(a0, fL1[0], c); c = MFMA(a1, fL1[1], c);
          c = MFMA(a2, fL1[2], c); c = MFMA(a3, fL1[3], c);
          hqa[g * SP + nt16 + col] = f2bf(tanh_fast(sel4(c, g) + b1));
        }
      } else {
        f32x4 cE = MFMA(a0, fL1[3], z4);              // emit L1 (z only)
        hea[g * SP + nt16 + col] = f2bf(tanh_fast(sel4(cE, g) + b1e));
        if (t < Tdim) {
          f32x4 c = z4;
          c = MFMA(a0, fL1[0], c); c = MFMA(a1, fL1[1], c); c = MFMA(a2, fL1[2], c);
          hpa[g * SP + nt16 + col] = f2bf(tanh_fast(sel4(c, g) + b1));
        }
      }
    }
    BAR();

    // ======== PHASE 2: L2 (q | p+e) + commits + KL(t-1) + NLL(t-2) ========
    {
      const f32x4 z4 = {0.f, 0.f, 0.f, 0.f};
      if (w < 8) {
        if (t < Tdim) {
          s16x8 a0 = *(const s16x8*)A2,        a1 = *(const s16x8*)(A2 + 32);
          s16x8 a2 = *(const s16x8*)(A2 + 64), a3 = *(const s16x8*)(A2 + 96);
          f32x4 c = z4;
          c = MFMA(a0, fL2[0], c); c = MFMA(a1, fL2[1], c);
          c = MFMA(a2, fL2[2], c); c = MFMA(a3, fL2[3], c);
          hqb[g * SP + nt16 + col] = f2bf(tanh_fast(sel4(c, g) + b2));
        }
      } else {
        s16x8 e0 = *(const s16x8*)A2e,        e1 = *(const s16x8*)(A2e + 32);
        s16x8 e2 = *(const s16x8*)(A2e + 64), e3 = *(const s16x8*)(A2e + 96);
        f32x4 ce = z4;
        ce = MFMA(e0, fX[0], ce); ce = MFMA(e1, fX[1], ce);
        ce = MFMA(e2, fX[2], ce); ce = MFMA(e3, fX[3], ce);
        heb[g * SP + nt16 + col] = f2bf(tanh_fast(sel4(ce, g) + b2e));
        if (t < Tdim) {
          s16x8 a0 = *(const s16x8*)A2,        a1 = *(const s16x8*)(A2 + 32);
          s16x8 a2 = *(const s16x8*)(A2 + 64), a3 = *(const s16x8*)(A2 + 96);
          f32x4 c = z4;
          c = MFMA(a0, fL2[0], c); c = MFMA(a1, fL2[1], c);
          c = MFMA(a2, fL2[2], c); c = MFMA(a3, fL2[3], c);
          hpb[g * SP + nt16 + col] = f2bf(tanh_fast(sel4(c, g) + b2));
        }
      }
      if (w < 4 && t < Tdim - 1) in_pq[w * SP + 32 + lane] = f2bf(xn);
      if ((w == 4 || w == 5) && t < Tdim - 1) {
        int off = (w - 4) * 64 + lane;
        in_pq[(off >> 5) * SP + 96 + (off & 31)] = f2bf(yn);
        y_f32[(t + 1) & 3][off] = yn;
      }
      if (w == 6 || w == 7) {
        int off = (w - 6) * 64 + lane, s = off >> 5, zd = off & 31;
        if (t >= 1) {
          float2 q = *(const float2*)&out_q2[s][zd][0];
          float2 p = *(const float2*)&out_p2[s][zd][0];
          float dm = q.x - p.x;
          kl_acc += p.y - q.y + (__expf(q.y) + dm * dm) / (__expf(p.y) + 1e-12f);
        }
        if (t >= 2) {
          float2 e = *(const float2*)&emit_o2[s][zd][0];
          float d = y_f32[(t - 2) & 3][off] - e.x;
          nll_acc += e.y + d * d * __expf(-e.y);
        }
      }
    }
    BAR();

    // ======== PHASE 3: heads (q w0-1 +sample | p w2-3) + e-L3 (w4-7) ========
    {
      const f32x4 z4 = {0.f, 0.f, 0.f, 0.f};
      if (w < 4) {
        if (t < Tdim) {
          s16x8 a0 = *(const s16x8*)A3,        a1 = *(const s16x8*)(A3 + 32);
          s16x8 a2 = *(const s16x8*)(A3 + 64), a3 = *(const s16x8*)(A3 + 96);
          const s16x8* pool = (w < 2) ? &poolQ3[0][0] : &poolP3[0][0];
          const int mslot = (w & 1) * 4;     // mu n-tile slots
          f32x4 cM = z4, cL = z4;
          cM = MFMA(a0, pool[(mslot + 0) * 64 + lane], cM);
          cM = MFMA(a1, pool[(mslot + 1) * 64 + lane], cM);
          cM = MFMA(a2, pool[(mslot + 2) * 64 + lane], cM);
          cM = MFMA(a3, pool[(mslot + 3) * 64 + lane], cM);
          cL = MFMA(a0, pool[(8 + mslot + 0) * 64 + lane], cL);
          cL = MFMA(a1, pool[(8 + mslot + 1) * 64 + lane], cL);
          cL = MFMA(a2, pool[(8 + mslot + 2) * 64 + lane], cL);
          cL = MFMA(a3, pool[(8 + mslot + 3) * 64 + lane], cL);
          float mu = sel4(cM, g) + b3m;
          float lv = clampf(sel4(cL, g) + b3l);
          if (w < 2) {
            float z = mu + __expf(0.5f * lv) * epsb[t & 3][g * 32 + w * 16 + col];
            in_pq[g * SP + w * 16 + col] = f2bf(z);
            *(float2*)&out_q2[g][w * 16 + col][0] = make_float2(mu, lv);
          } else {
            *(float2*)&out_p2[g][(w - 2) * 16 + col][0] = make_float2(mu, lv);
          }
        }
      } else if (w < 8) {
        s16x8 a0 = *(const s16x8*)A3,        a1 = *(const s16x8*)(A3 + 32);
        s16x8 a2 = *(const s16x8*)(A3 + 64), a3 = *(const s16x8*)(A3 + 96);
        f32x4 c = z4;
        c = MFMA(a0, fX[0], c); c = MFMA(a1, fX[1], c);
        c = MFMA(a2, fX[2], c); c = MFMA(a3, fX[3], c);
        float v = sel4(c, g) + b3m;
        if (w < 6) {        // mu_y cols (w-4)*16..
          if (t >= 1)
            gout[((size_t)(base + g) * Tdim + (t - 1)) * DOUT + (w - 4) * 16 + col] = v;
          emit_o2[g][(w - 4) * 16 + col][0] = v;
        } else {            // lv_y cols (w-6)*16.. (stored clamped)
          emit_o2[g][(w - 6) * 16 + col][1] = clampf(v);
        }
      }
    }
    BAR();
  }

  // final NLL (step 511): emit_o2 from flush iter, y ring slot 3
  if (w == 6 || w == 7) {
    int off = (w - 6) * 64 + lane, s = off >> 5, zd = off & 31;
    float2 e = *(const float2*)&emit_o2[s][zd][0];
    float d = y_f32[(Tdim - 1) & 3][off] - e.x;
    nll_acc += e.y + d * d * __expf(-e.y);
  }

  // reduce: w6/w7 hold both accumulators
  float vn = nll_acc, vk = kl_acc;
#pragma unroll
  for (int o = 32; o > 0; o >>= 1) { vn += __shfl_down(vn, o, 64); vk += __shfl_down(vk, o, 64); }
  if ((w == 6 || w == 7) && lane == 0) { redsb[(w - 6) * 2] = vn; redsb[(w - 6) * 2 + 1] = vk; }
  BAR();
  if (tid == 0) {
    gws[wg]       = redsb[0] + redsb[2];
    gws[NWG + wg] = redsb[1] + redsb[3];
  }
}

// ---------------- finalize: reduce 256 partials ----------------
__global__ void dssm_fin(const float* __restrict__ gws, float* __restrict__ gout) {
  __shared__ float sb2[8];
  int tid = threadIdx.x;   // 256
  int w = tid >> 6, lane = tid & 63;
  float vn = gws[tid], vk = gws[NWG + tid];
#pragma unroll
  for (int o = 32; o > 0; o >>= 1) { vn += __shfl_down(vn, o, 64); vk += __shfl_down(vk, o, 64); }
  if (lane == 0) { sb2[w] = vn; sb2[4 + w] = vk; }
  __syncthreads();
  if (tid == 0) {
    float sn = 0.f, sk = 0.f;
#pragma unroll
    for (int i = 0; i < 4; ++i) { sn += sb2[i]; sk += sb2[4 + i]; }
    const float inv = 1.0f / (float)((size_t)Bdim * Tdim);
    float nll = 0.5f * (sn * inv + (float)DOUT * 1.8378770664093453f);
    float kl  = 0.5f * (sk * inv - (float)DZ);
    size_t o0 = (size_t)Bdim * Tdim * DOUT;
    gout[o0 + 0] = nll + kl;
    gout[o0 + 1] = nll;
    gout[o0 + 2] = kl;
  }
}

extern "C" void kernel_launch(void* const* d_in, const int* in_sizes, int n_in,
                              void* d_out, int out_size, void* d_ws, size_t ws_size,
                              hipStream_t stream) {
  (void)in_sizes; (void)n_in; (void)out_size; (void)ws_size;
  const float* gx  = (const float*)d_in[0];
  const float* gy  = (const float*)d_in[1];
  const float* pW1 = (const float*)d_in[2];  const float* pb1 = (const float*)d_in[3];
  const float* pW2 = (const float*)d_in[4];  const float* pb2 = (const float*)d_in[5];
  const float* pW3 = (const float*)d_in[6];  const float* pb3 = (const float*)d_in[7];
  const float* qW1 = (const float*)d_in[8];  const float* qb1 = (const float*)d_in[9];
  const float* qW2 = (const float*)d_in[10]; const float* qb2 = (const float*)d_in[11];
  const float* qW3 = (const float*)d_in[12]; const float* qb3 = (const float*)d_in[13];
  const float* eW1 = (const float*)d_in[14]; const float* eb1 = (const float*)d_in[15];
  const float* eW2 = (const float*)d_in[16]; const float* eb2 = (const float*)d_in[17];
  const float* eW3 = (const float*)d_in[18]; const float* eb3 = (const float*)d_in[19];
  const float* z0mu = (const float*)d_in[20];
  const float* z0lv = (const float*)d_in[21];
  float* gout = (float*)d_out;
  float* gws  = (float*)d_ws;

  unsigned ka0, ka1, kb0, kb1;
  tf2x32(0u, 42u, 0u, 0u, ka0, ka1);   // fold_in(key(42), 0) -> eps0 key
  tf2x32(0u, 42u, 0u, 1u, kb0, kb1);   // fold_in(key(42), 1) -> eps key

  dssm_main<<<NWG, NTHR, 0, stream>>>(gx, gy,
      pW1, pb1, pW2, pb2, pW3, pb3,
      qW1, qb1, qW2, qb2, qW3, qb3,
      eW1, eb1, eW2, eb2, eW3, eb3,
      z0mu, z0lv, gout, gws, ka0, ka1, kb0, kb1);
  dssm_fin<<<1, 256, 0, stream>>>(gws, gout);
}